// Round 11
// baseline (2390.590 us; speedup 1.0000x reference)
//
#include <hip/hip_runtime.h>

typedef _Float16 half8 __attribute__((ext_vector_type(8)));
typedef float floatx4 __attribute__((ext_vector_type(4)));
typedef unsigned uintx4 __attribute__((ext_vector_type(4)));
typedef unsigned long long u64;

#define T_STEPS 512
#define IN_DIM 256
#define HID 512
#define RING 8

// ---- R15 = R10 (poll/publish/waits verbatim) + cross-step h0 prefetch ----
// When step t's dual poll observed flags0>=t+2 (skip0), the 16 h0[t+1] loads
// are issued at END of step t in one asm block after the 2 h1 stores, ending
// in s_waitcnt vmcnt(16): in-order vmcnt retirement => waits exactly the 2
// stores (publish safety == R10), loads fly across the loop edge. Next step
// top: vmcnt(0) leftover (~600cy) instead of a full ldfrag RTT (~1400cy).
// skip0 is LDS-broadcast (double-buffered, synced by the mid-step barrier).
// R13/R14's sampled-poll machinery is reverted (3x evidence it loses).

__device__ inline float sig_f(float x) { return 1.f / (1.f + __expf(-x)); }
__device__ inline float tanh_f(float x) {
  float t = __expf(-2.f * fabsf(x));
  return copysignf((1.f - t) / (1.f + t), x);
}
__device__ inline unsigned umin_(unsigned a, unsigned b) { return a < b ? a : b; }

__device__ inline void cstore_pair(_Float16* p, float a, float b) {
  union { unsigned u; _Float16 h[2]; } pk;
  pk.h[0] = (_Float16)a; pk.h[1] = (_Float16)b;
  __hip_atomic_store((unsigned*)p, pk.u, __ATOMIC_RELAXED, __HIP_MEMORY_SCOPE_AGENT);
}
__device__ inline void cstore64(_Float16* p, u64 v) {
  __hip_atomic_store((u64*)p, v, __ATOMIC_RELAXED, __HIP_MEMORY_SCOPE_AGENT);
}
__device__ inline u64 cload64(const _Float16* p) {
  return __hip_atomic_load((const u64*)p, __ATOMIC_RELAXED, __HIP_MEMORY_SCOPE_AGENT);
}
__device__ inline half8 cload_h8(const _Float16* p) {
  union { u64 u[2]; half8 v; } r;
  r.u[0] = cload64(p);
  r.u[1] = cload64(p + 4);
  return r.v;
}

// 16-load frag-linear body (R10-proven): 4 bases %16..%19, outputs %0..%15.
#define LDF16_LOADS                                             \
  "global_load_dwordx4 %0, %16, off sc0 sc1\n\t"                \
  "global_load_dwordx4 %1, %16, off offset:1024 sc0 sc1\n\t"    \
  "global_load_dwordx4 %2, %16, off offset:2048 sc0 sc1\n\t"    \
  "global_load_dwordx4 %3, %16, off offset:3072 sc0 sc1\n\t"    \
  "global_load_dwordx4 %4, %17, off sc0 sc1\n\t"                \
  "global_load_dwordx4 %5, %17, off offset:1024 sc0 sc1\n\t"    \
  "global_load_dwordx4 %6, %17, off offset:2048 sc0 sc1\n\t"    \
  "global_load_dwordx4 %7, %17, off offset:3072 sc0 sc1\n\t"    \
  "global_load_dwordx4 %8, %18, off sc0 sc1\n\t"                \
  "global_load_dwordx4 %9, %18, off offset:1024 sc0 sc1\n\t"    \
  "global_load_dwordx4 %10, %18, off offset:2048 sc0 sc1\n\t"   \
  "global_load_dwordx4 %11, %18, off offset:3072 sc0 sc1\n\t"   \
  "global_load_dwordx4 %12, %19, off sc0 sc1\n\t"               \
  "global_load_dwordx4 %13, %19, off offset:1024 sc0 sc1\n\t"   \
  "global_load_dwordx4 %14, %19, off offset:2048 sc0 sc1\n\t"   \
  "global_load_dwordx4 %15, %19, off offset:3072 sc0 sc1"

__device__ inline void ldfrag16(const char* b0, half8 (&r)[16]) {
  const char* b1 = b0 + 4096;
  const char* b2 = b0 + 8192;
  const char* b3 = b0 + 12288;
  floatx4 t0, t1, t2, t3, t4, t5, t6, t7, t8, t9, t10, t11, t12, t13, t14, t15;
  asm volatile(LDF16_LOADS "\n\t"
               "s_waitcnt vmcnt(0)"
               : "=&v"(t0), "=&v"(t1), "=&v"(t2), "=&v"(t3),
                 "=&v"(t4), "=&v"(t5), "=&v"(t6), "=&v"(t7),
                 "=&v"(t8), "=&v"(t9), "=&v"(t10), "=&v"(t11),
                 "=&v"(t12), "=&v"(t13), "=&v"(t14), "=&v"(t15)
               : "v"(b0), "v"(b1), "v"(b2), "v"(b3)
               : "memory");
  r[0] = __builtin_bit_cast(half8, t0);   r[1] = __builtin_bit_cast(half8, t1);
  r[2] = __builtin_bit_cast(half8, t2);   r[3] = __builtin_bit_cast(half8, t3);
  r[4] = __builtin_bit_cast(half8, t4);   r[5] = __builtin_bit_cast(half8, t5);
  r[6] = __builtin_bit_cast(half8, t6);   r[7] = __builtin_bit_cast(half8, t7);
  r[8] = __builtin_bit_cast(half8, t8);   r[9] = __builtin_bit_cast(half8, t9);
  r[10] = __builtin_bit_cast(half8, t10); r[11] = __builtin_bit_cast(half8, t11);
  r[12] = __builtin_bit_cast(half8, t12); r[13] = __builtin_bit_cast(half8, t13);
  r[14] = __builtin_bit_cast(half8, t14); r[15] = __builtin_bit_cast(half8, t15);
}

// Block-level wait: lane i min-reduces block i's 4 per-wave sub-flags (16B).
__device__ inline void waitf4(const unsigned* fg, unsigned tg) {
  if (tg == 0) return;
  const unsigned* p = fg + (threadIdx.x & 63) * 32;
  int it = 0;
  for (;;) {
    floatx4 t;
    asm volatile("global_load_dwordx4 %0, %1, off sc0 sc1\n\t"
                 "s_waitcnt vmcnt(0)"
                 : "=&v"(t) : "v"(p) : "memory");
    uintx4 u = __builtin_bit_cast(uintx4, t);
    unsigned m = umin_(umin_(u.x, u.y), umin_(u.z, u.w));
    if (__all((int)(m >= tg))) return;
    if (++it > 4) __builtin_amdgcn_s_sleep(1);
  }
}

// R10-proven fresh dual-poll: block until fg1>=tg1, sample fg0>=tg0.
__device__ inline bool waitf4_dual(const unsigned* fg1, unsigned tg1,
                                   const unsigned* fg0, unsigned tg0) {
  const unsigned* p1 = fg1 + (threadIdx.x & 63) * 32;
  const unsigned* p0 = fg0 + (threadIdx.x & 63) * 32;
  unsigned m1, m0v;
  int it = 0;
  for (;;) {
    floatx4 t1, t0;
    asm volatile("global_load_dwordx4 %0, %2, off sc0 sc1\n\t"
                 "global_load_dwordx4 %1, %3, off sc0 sc1\n\t"
                 "s_waitcnt vmcnt(0)"
                 : "=&v"(t1), "=&v"(t0)
                 : "v"(p1), "v"(p0)
                 : "memory");
    uintx4 u1 = __builtin_bit_cast(uintx4, t1);
    uintx4 u0 = __builtin_bit_cast(uintx4, t0);
    m1 = umin_(umin_(u1.x, u1.y), umin_(u1.z, u1.w));
    m0v = umin_(umin_(u0.x, u0.y), umin_(u0.z, u0.w));
    if (__all((int)(m1 >= tg1))) break;
    if (++it > 4) __builtin_amdgcn_s_sleep(1);
  }
  return (bool)__all((int)(m0v >= tg0));
}

__device__ inline floatx4 mfma16(half8 a, half8 b, floatx4 c) {
  return __builtin_amdgcn_mfma_f32_16x16x32_f16(a, b, c, 0, 0, 0);
}

__global__ void init_kernel(const float* __restrict__ x, const float* __restrict__ hc,
                            _Float16* __restrict__ x16, _Float16* __restrict__ h0b,
                            _Float16* __restrict__ h1b, unsigned* __restrict__ flagbase) {
  size_t i = (size_t)blockIdx.x * blockDim.x + threadIdx.x;
  size_t stride = (size_t)gridDim.x * blockDim.x;
  // x -> frag-linear fp16 (R10-proven).
  const size_t nch = (size_t)T_STEPS * 64 * 32;
  for (size_t n = i; n < nch; n += stride) {
    size_t tr = n >> 5;
    int cc = (int)(n & 31);
    int row = (int)(tr & 63);
    size_t t = tr >> 6;
    const float* src = x + (tr * 256 + (size_t)cc * 8);
    floatx4 v0 = *(const floatx4*)src;
    floatx4 v1 = *(const floatx4*)(src + 4);
    half8 h;
    h[0] = (_Float16)v0.x; h[1] = (_Float16)v0.y; h[2] = (_Float16)v0.z; h[3] = (_Float16)v0.w;
    h[4] = (_Float16)v1.x; h[5] = (_Float16)v1.y; h[6] = (_Float16)v1.z; h[7] = (_Float16)v1.w;
    _Float16* dstp = x16 + t * 16384 + (size_t)(row >> 4) * 4096 +
                     (size_t)(cc >> 2) * 512 + (size_t)((row & 15) + 16 * (cc & 3)) * 8;
    *(half8*)dstp = h;
  }
  // h seeds in frag-linear layout (R10-proven).
  if (i < 8192) {
    int which = (int)(i >> 12);
    int idx = (int)(i & 4095);
    int m = idx >> 6, cc = idx & 63;
    const float* src = hc + (size_t)which * 32768 + (size_t)m * 512 + (size_t)cc * 8;
    union { u64 u[2]; half8 v; } pk;
#pragma unroll
    for (int e = 0; e < 8; ++e) pk.v[e] = (_Float16)src[e];
    _Float16* base = which ? (h1b + 32768) : (h0b + (size_t)(RING - 1) * 32768);
    _Float16* dstp = base + (size_t)(m >> 4) * 8192 + (size_t)(cc >> 2) * 512 +
                     (size_t)((m & 15) + 16 * (cc & 3)) * 8;
    cstore64(dstp, pk.u[0]);
    cstore64(dstp + 4, pk.u[1]);
  }
  if (i < 4096) {
    __hip_atomic_store(flagbase + i, 0u, __ATOMIC_RELAXED, __HIP_MEMORY_SCOPE_AGENT);
  }
}

__global__ __launch_bounds__(256, 1) void lstm_kernel(
    const _Float16* __restrict__ x16, _Float16* __restrict__ h0b, _Float16* __restrict__ h1b,
    unsigned* __restrict__ flags0, unsigned* __restrict__ flags1,
    const float* __restrict__ W_ih0, const float* __restrict__ W_hh0,
    const float* __restrict__ b_ih0, const float* __restrict__ b_hh0,
    const float* __restrict__ W_ih1, const float* __restrict__ W_hh1,
    const float* __restrict__ b_ih1, const float* __restrict__ b_hh1,
    const float* __restrict__ W_out, const float* __restrict__ b_out,
    const float* __restrict__ hc, float* __restrict__ out) {
  __shared__ __align__(16) _Float16 wlds[32 * 1032];
  __shared__ unsigned skLDS[2];  // skip0 broadcast, double-buffered (race-free
                                 // across the mid-step barrier epochs)

  const int bq = blockIdx.x;
  const bool isL0 = bq < 64;
  const int q = isL0 ? bq : bq - 64;
  const int col0 = q * 8;
  const int Ka = isL0 ? IN_DIM : HID;
  const int K = Ka + HID;
  const int WP = K + 8;
  const int layer = isL0 ? 0 : 1;
  const float* Wa = isL0 ? W_ih0 : W_ih1;
  const float* Wb = isL0 ? W_hh0 : W_hh1;
  const float* bia = isL0 ? b_ih0 : b_ih1;
  const float* bib = isL0 ? b_hh0 : b_hh1;

  for (int idx = threadIdx.x; idx < 32 * K; idx += 256) {
    int r = idx / K;
    int k = idx - r * K;
    int g = r >> 3, j = r & 7;
    int grow = g * HID + col0 + j;  // PyTorch gate order i,f,g,o
    float w = (k < Ka) ? Wa[(size_t)grow * Ka + k] : Wb[(size_t)grow * HID + (k - Ka)];
    wlds[r * WP + k] = (_Float16)w;
  }
  __syncthreads();

  const int lane = threadIdx.x & 63;
  const int wv = threadIdx.x >> 6;
  const int lrow = lane & 15;
  const int kq = (lane >> 4) * 8;
  const _Float16* wrow0 = wlds + lrow * WP;
  const _Float16* wrow1 = wlds + (16 + lrow) * WP;

  half8 breg0[16], breg1[16];
#pragma unroll
  for (int c = 0; c < 16; ++c) {
    breg0[c] = *(const half8*)(wrow0 + Ka + c * 32 + kq);
    breg1[c] = *(const half8*)(wrow1 + Ka + c * 32 + kq);
  }

  // Register-gate-phase constants (R8-proven mapping).
  const int bsel = lrow >> 3;
  const int jc = lrow & 7;
  const int rbase = wv * 16 + ((lane >> 4) << 2) + 2 * bsel;
  const int colg = col0 + jc;
  const float bi_ = bia[colg] + bib[colg];
  const float bf_ = bia[HID + colg] + bib[HID + colg];
  const float bg_ = bia[2 * HID + colg] + bib[2 * HID + colg];
  const float bo_ = bia[3 * HID + colg] + bib[3 * HID + colg];
  float cst0 = hc[(size_t)(2 + layer) * 32768 + (size_t)(rbase + 0) * HID + colg];
  float cst1 = hc[(size_t)(2 + layer) * 32768 + (size_t)(rbase + 1) * HID + colg];

  unsigned* myflag = (isL0 ? flags0 : flags1) + q * 32 + wv;

  const size_t rd_off = (size_t)wv * 16384 + (size_t)lane * 16;  // bytes
  const size_t st_off = (size_t)wv * 8192 + (size_t)(q >> 2) * 512 +
                        (size_t)((rbase & 15) + ((q & 3) << 4)) * 8 + jc;  // halfwords

  bool skip0r = false;  // L1: top flags0 wait skippable (cert seen last step)
  bool pref = false;    // L1: f-prefetch in flight across the loop edge
  half8 f[16];
  floatx4 pf0, pf1, pf2, pf3, pf4, pf5, pf6, pf7,
          pf8, pf9, pf10, pf11, pf12, pf13, pf14, pf15;

  for (int t = 0; t < T_STEPS; ++t) {
    floatx4 acc0 = {0.f, 0.f, 0.f, 0.f};
    floatx4 acc1 = {0.f, 0.f, 0.f, 0.f};
    _Float16* dst;
    unsigned skv = 0;

    if (isL0) {
      // X phase (plain frag-linear loads, no cross-block dep).
      const _Float16* xw = x16 + (size_t)t * 16384 + (size_t)wv * 4096 + (size_t)lane * 8;
#pragma unroll
      for (int c = 0; c < 8; ++c) {
        half8 a = *(const half8*)(xw + c * 512);
        half8 b0v = *(const half8*)(wrow0 + c * 32 + kq);
        half8 b1v = *(const half8*)(wrow1 + c * 32 + kq);
        acc0 = mfma16(a, b0v, acc0);
        acc1 = mfma16(a, b1v, acc1);
      }
      // Merged wait: wave0 -> peers' h0[t-1]; wave1 -> ring slot free.
      if (threadIdx.x < 64) waitf4(flags0, (unsigned)t);
      else if (threadIdx.x < 128) waitf4(flags1, (t >= RING) ? (unsigned)(t - RING + 1) : 0u);
      __syncthreads();
      asm volatile("" ::: "memory");
      const char* a1p = (const char*)(h0b + (size_t)((t - 1) & (RING - 1)) * 32768) + rd_off;
      ldfrag16(a1p, f);
#pragma unroll
      for (int c = 0; c < 16; ++c) {
        acc0 = mfma16(f[c], breg0[c], acc0);
        acc1 = mfma16(f[c], breg1[c], acc1);
      }
      dst = h0b + (size_t)(t & (RING - 1)) * 32768;
    } else {
      // Phase 1: consume prefetched h0[t] or fall back to the R10 path.
      if (!pref) {
        if (threadIdx.x < 64 && !skip0r) waitf4(flags0, (unsigned)(t + 1));
        __syncthreads();
        asm volatile("" ::: "memory");
        const char* a0p = (const char*)(h0b + (size_t)(t & (RING - 1)) * 32768) + rd_off;
        ldfrag16(a0p, f);
      } else {
        // Complete the in-flight prefetch; "+v" keeps the registers pinned
        // through the wait (rule-18 guard: sched_barrier right after).
        asm volatile("s_waitcnt vmcnt(0)"
                     : "+v"(pf0), "+v"(pf1), "+v"(pf2), "+v"(pf3),
                       "+v"(pf4), "+v"(pf5), "+v"(pf6), "+v"(pf7),
                       "+v"(pf8), "+v"(pf9), "+v"(pf10), "+v"(pf11),
                       "+v"(pf12), "+v"(pf13), "+v"(pf14), "+v"(pf15)
                     :: "memory");
        __builtin_amdgcn_sched_barrier(0);
        f[0] = __builtin_bit_cast(half8, pf0);   f[1] = __builtin_bit_cast(half8, pf1);
        f[2] = __builtin_bit_cast(half8, pf2);   f[3] = __builtin_bit_cast(half8, pf3);
        f[4] = __builtin_bit_cast(half8, pf4);   f[5] = __builtin_bit_cast(half8, pf5);
        f[6] = __builtin_bit_cast(half8, pf6);   f[7] = __builtin_bit_cast(half8, pf7);
        f[8] = __builtin_bit_cast(half8, pf8);   f[9] = __builtin_bit_cast(half8, pf9);
        f[10] = __builtin_bit_cast(half8, pf10); f[11] = __builtin_bit_cast(half8, pf11);
        f[12] = __builtin_bit_cast(half8, pf12); f[13] = __builtin_bit_cast(half8, pf13);
        f[14] = __builtin_bit_cast(half8, pf14); f[15] = __builtin_bit_cast(half8, pf15);
      }
#pragma unroll
      for (int c = 0; c < 16; ++c) {
        half8 b0v = *(const half8*)(wrow0 + c * 32 + kq);
        half8 b1v = *(const half8*)(wrow1 + c * 32 + kq);
        acc0 = mfma16(f[c], b0v, acc0);
        acc1 = mfma16(f[c], b1v, acc1);
      }
      // R10-verbatim fresh dual poll + LDS broadcast of skip0.
      if (threadIdx.x < 64) {
        bool sk = waitf4_dual(flags1, (unsigned)t, flags0, (unsigned)(t + 2));
        if (threadIdx.x == 0) skLDS[t & 1] = sk ? 1u : 0u;
      }
      __syncthreads();
      asm volatile("" ::: "memory");
      skv = skLDS[t & 1];
      const char* a1p = (const char*)(h1b + (size_t)((t - 1) & 1) * 32768) + rd_off;
      ldfrag16(a1p, f);
#pragma unroll
      for (int c = 0; c < 16; ++c) {
        acc0 = mfma16(f[c], breg0[c], acc0);
        acc1 = mfma16(f[c], breg1[c], acc1);
      }
      dst = h1b + (size_t)(t & 1) * 32768;
    }

    // ---- register gate phase (R8-proven) ----
    float s00 = __shfl_xor(bsel ? (float)acc0[0] : (float)acc0[2], 8);
    float s01 = __shfl_xor(bsel ? (float)acc0[1] : (float)acc0[3], 8);
    float s10 = __shfl_xor(bsel ? (float)acc1[0] : (float)acc1[2], 8);
    float s11 = __shfl_xor(bsel ? (float)acc1[1] : (float)acc1[3], 8);
    float hv0, hv1;
    {
      float o0 = bsel ? (float)acc0[2] : (float)acc0[0];
      float o1 = bsel ? (float)acc1[2] : (float)acc1[0];
      float gi = bsel ? s00 : o0;
      float gf = bsel ? o0 : s00;
      float gg = bsel ? s10 : o1;
      float go = bsel ? o1 : s10;
      float c = sig_f(gf + bf_) * cst0 + sig_f(gi + bi_) * tanh_f(gg + bg_);
      cst0 = c;
      hv0 = sig_f(go + bo_) * tanh_f(c);
    }
    {
      float o0 = bsel ? (float)acc0[3] : (float)acc0[1];
      float o1 = bsel ? (float)acc1[3] : (float)acc1[1];
      float gi = bsel ? s01 : o0;
      float gf = bsel ? o0 : s01;
      float gg = bsel ? s11 : o1;
      float go = bsel ? o1 : s11;
      float c = sig_f(gf + bf_) * cst1 + sig_f(gi + bi_) * tanh_f(gg + bg_);
      cst1 = c;
      hv1 = sig_f(go + bo_) * tanh_f(c);
    }
    float hx0 = __shfl_xor(hv0, 1);
    float hx1 = __shfl_xor(hv1, 1);
    if ((jc & 1) == 0) {
      _Float16* sb = dst + st_off;
      cstore_pair(sb, hv0, hx0);       // exactly 2 store instructions in the
      cstore_pair(sb + 8, hv1, hx1);   // wave's stream (exec-masked, counted)
    }

    // Release.
    if (isL0) {
      asm volatile("s_waitcnt vmcnt(0)" ::: "memory");
      if ((threadIdx.x & 63) == 0) {
        __hip_atomic_store(myflag, (unsigned)(t + 1), __ATOMIC_RELAXED,
                           __HIP_MEMORY_SCOPE_AGENT);
      }
      asm volatile("" ::: "memory");
    } else {
      __builtin_amdgcn_sched_barrier(0);
      if (skv && t < T_STEPS - 1) {
        // Prefetch h0[t+1] (cert: skv == flags0>=t+2 observed this step).
        // vmcnt(16) waits the 2 stores only (in-order retirement); the 16
        // loads stay in flight across the loop edge into pf0..pf15.
        const char* nb0 = (const char*)(h0b + (size_t)((t + 1) & (RING - 1)) * 32768) + rd_off;
        const char* nb1 = nb0 + 4096;
        const char* nb2 = nb0 + 8192;
        const char* nb3 = nb0 + 12288;
        asm volatile(LDF16_LOADS "\n\t"
                     "s_waitcnt vmcnt(16)"
                     : "=&v"(pf0), "=&v"(pf1), "=&v"(pf2), "=&v"(pf3),
                       "=&v"(pf4), "=&v"(pf5), "=&v"(pf6), "=&v"(pf7),
                       "=&v"(pf8), "=&v"(pf9), "=&v"(pf10), "=&v"(pf11),
                       "=&v"(pf12), "=&v"(pf13), "=&v"(pf14), "=&v"(pf15)
                     : "v"(nb0), "v"(nb1), "v"(nb2), "v"(nb3)
                     : "memory");
        pref = true;
      } else {
        asm volatile("s_waitcnt vmcnt(0)" ::: "memory");
        pref = false;
      }
      skip0r = (skv != 0);
      if ((threadIdx.x & 63) == 0) {
        __hip_atomic_store(myflag, (unsigned)(t + 1), __ATOMIC_RELAXED,
                           __HIP_MEMORY_SCOPE_AGENT);
      }
      asm volatile("" ::: "memory");
    }
  }

  // Final linear on L0 blocks: out[64,256] = h1[511] @ W_out^T + b_out.
  if (isL0) {
    if (threadIdx.x < 64) waitf4(flags1, (unsigned)T_STEPS);
    __syncthreads();
    asm volatile("" ::: "memory");
    const int oc = q * 4 + (threadIdx.x & 3);
    const int m = threadIdx.x >> 2;
    const float* wrow = W_out + (size_t)oc * HID;
    const _Float16* hbase = h1b + 32768;  // h1[511] at parity 1, frag-linear
    float sum = 0.f;
#pragma unroll 4
    for (int hh = 0; hh < 64; ++hh) {
      const _Float16* cp = hbase + (size_t)(m >> 4) * 8192 + (size_t)(hh >> 2) * 512 +
                           (size_t)((m & 15) + 16 * (hh & 3)) * 8;
      half8 hvv = cload_h8(cp);
#pragma unroll
      for (int e = 0; e < 8; ++e) sum += (float)hvv[e] * wrow[hh * 8 + e];
    }
    out[m * 256 + oc] = sum + b_out[oc];
  }
}

extern "C" void kernel_launch(void* const* d_in, const int* in_sizes, int n_in,
                              void* d_out, int out_size, void* d_ws, size_t ws_size,
                              hipStream_t stream) {
  const float* x     = (const float*)d_in[0];
  const float* hc    = (const float*)d_in[1];
  const float* W_ih0 = (const float*)d_in[2];
  const float* W_hh0 = (const float*)d_in[3];
  const float* b_ih0 = (const float*)d_in[4];
  const float* b_hh0 = (const float*)d_in[5];
  const float* W_ih1 = (const float*)d_in[6];
  const float* W_hh1 = (const float*)d_in[7];
  const float* b_ih1 = (const float*)d_in[8];
  const float* b_hh1 = (const float*)d_in[9];
  const float* W_out = (const float*)d_in[10];
  const float* b_out = (const float*)d_in[11];
  float* out = (float*)d_out;

  char* ws = (char*)d_ws;
  _Float16* x16 = (_Float16*)ws;                              // 16 MB (frag-linear)
  _Float16* h0b = (_Float16*)(ws + 16777216);                 // 8 x 64 KB ring
  _Float16* h1b = (_Float16*)(ws + 16777216 + 8 * 65536);     // 2 x 64 KB
  unsigned* flags0 = (unsigned*)(ws + 16777216 + 10 * 65536);           // 8 KB
  unsigned* flags1 = (unsigned*)(ws + 16777216 + 10 * 65536 + 8192);    // 8 KB

  init_kernel<<<2048, 256, 0, stream>>>(x, hc, x16, h0b, h1b, flags0);
  lstm_kernel<<<128, 256, 0, stream>>>(x16, h0b, h1b, flags0, flags1,
                                       W_ih0, W_hh0, b_ih0, b_hh0,
                                       W_ih1, W_hh1, b_ih1, b_hh1,
                                       W_out, b_out, hc, out);
}

// Round 12
// 1858.559 us; speedup vs baseline: 1.2863x; 1.2863x over previous
//
#include <hip/hip_runtime.h>

typedef _Float16 half8 __attribute__((ext_vector_type(8)));
typedef _Float16 half4 __attribute__((ext_vector_type(4)));
typedef float floatx4 __attribute__((ext_vector_type(4)));
typedef unsigned uintx4 __attribute__((ext_vector_type(4)));
typedef unsigned long long u64;

#define T_STEPS 512
#define IN_DIM 256
#define HID 512
#define RING 8

// ---- R16 = R10 byte-identical resubmission (calibration + lock-in) ----
// R11..R15 all regressed vs R10's 1776us; every structural edit to R10's
// synchronization loses. This rerun pins the best kernel and measures
// cross-container variance.

__device__ inline float sig_f(float x) { return 1.f / (1.f + __expf(-x)); }
__device__ inline float tanh_f(float x) {
  float t = __expf(-2.f * fabsf(x));
  return copysignf((1.f - t) / (1.f + t), x);
}
__device__ inline unsigned umin_(unsigned a, unsigned b) { return a < b ? a : b; }

// ---- LLC-coherent (agent-scope) accessors — proven R3/R4/R8 ----
__device__ inline void cstore_pair(_Float16* p, float a, float b) {
  union { unsigned u; _Float16 h[2]; } pk;
  pk.h[0] = (_Float16)a; pk.h[1] = (_Float16)b;
  __hip_atomic_store((unsigned*)p, pk.u, __ATOMIC_RELAXED, __HIP_MEMORY_SCOPE_AGENT);
}
__device__ inline void cstore64(_Float16* p, u64 v) {
  __hip_atomic_store((u64*)p, v, __ATOMIC_RELAXED, __HIP_MEMORY_SCOPE_AGENT);
}
__device__ inline u64 cload64(const _Float16* p) {
  return __hip_atomic_load((const u64*)p, __ATOMIC_RELAXED, __HIP_MEMORY_SCOPE_AGENT);
}
__device__ inline half8 cload_h8(const _Float16* p) {
  union { u64 u[2]; half8 v; } r;
  r.u[0] = cload64(p);
  r.u[1] = cload64(p + 4);
  return r.v;
}

// Coalesced fragment-linear load: 16 frags, 4 base pointers (offset imm <=
// 4095), one waitcnt. b0 = snapshot + wv*16384 + lane*16 (bytes).
__device__ inline void ldfrag16(const char* b0, half8 (&r)[16]) {
  const char* b1 = b0 + 4096;
  const char* b2 = b0 + 8192;
  const char* b3 = b0 + 12288;
  floatx4 t0, t1, t2, t3, t4, t5, t6, t7, t8, t9, t10, t11, t12, t13, t14, t15;
  asm volatile(
      "global_load_dwordx4 %0, %16, off sc0 sc1\n\t"
      "global_load_dwordx4 %1, %16, off offset:1024 sc0 sc1\n\t"
      "global_load_dwordx4 %2, %16, off offset:2048 sc0 sc1\n\t"
      "global_load_dwordx4 %3, %16, off offset:3072 sc0 sc1\n\t"
      "global_load_dwordx4 %4, %17, off sc0 sc1\n\t"
      "global_load_dwordx4 %5, %17, off offset:1024 sc0 sc1\n\t"
      "global_load_dwordx4 %6, %17, off offset:2048 sc0 sc1\n\t"
      "global_load_dwordx4 %7, %17, off offset:3072 sc0 sc1\n\t"
      "global_load_dwordx4 %8, %18, off sc0 sc1\n\t"
      "global_load_dwordx4 %9, %18, off offset:1024 sc0 sc1\n\t"
      "global_load_dwordx4 %10, %18, off offset:2048 sc0 sc1\n\t"
      "global_load_dwordx4 %11, %18, off offset:3072 sc0 sc1\n\t"
      "global_load_dwordx4 %12, %19, off sc0 sc1\n\t"
      "global_load_dwordx4 %13, %19, off offset:1024 sc0 sc1\n\t"
      "global_load_dwordx4 %14, %19, off offset:2048 sc0 sc1\n\t"
      "global_load_dwordx4 %15, %19, off offset:3072 sc0 sc1\n\t"
      "s_waitcnt vmcnt(0)"
      : "=&v"(t0), "=&v"(t1), "=&v"(t2), "=&v"(t3),
        "=&v"(t4), "=&v"(t5), "=&v"(t6), "=&v"(t7),
        "=&v"(t8), "=&v"(t9), "=&v"(t10), "=&v"(t11),
        "=&v"(t12), "=&v"(t13), "=&v"(t14), "=&v"(t15)
      : "v"(b0), "v"(b1), "v"(b2), "v"(b3)
      : "memory");
  r[0] = __builtin_bit_cast(half8, t0);   r[1] = __builtin_bit_cast(half8, t1);
  r[2] = __builtin_bit_cast(half8, t2);   r[3] = __builtin_bit_cast(half8, t3);
  r[4] = __builtin_bit_cast(half8, t4);   r[5] = __builtin_bit_cast(half8, t5);
  r[6] = __builtin_bit_cast(half8, t6);   r[7] = __builtin_bit_cast(half8, t7);
  r[8] = __builtin_bit_cast(half8, t8);   r[9] = __builtin_bit_cast(half8, t9);
  r[10] = __builtin_bit_cast(half8, t10); r[11] = __builtin_bit_cast(half8, t11);
  r[12] = __builtin_bit_cast(half8, t12); r[13] = __builtin_bit_cast(half8, t13);
  r[14] = __builtin_bit_cast(half8, t14); r[15] = __builtin_bit_cast(half8, t15);
}

// Wave-parallel wait: lane i min-reduces block i's 4 per-wave sub-flags (16B).
__device__ inline void waitf4(const unsigned* fg, unsigned tg) {
  if (tg == 0) return;
  const unsigned* p = fg + (threadIdx.x & 63) * 32;
  int it = 0;
  for (;;) {
    floatx4 t;
    asm volatile("global_load_dwordx4 %0, %1, off sc0 sc1\n\t"
                 "s_waitcnt vmcnt(0)"
                 : "=&v"(t) : "v"(p) : "memory");
    uintx4 u = __builtin_bit_cast(uintx4, t);
    unsigned m = umin_(umin_(u.x, u.y), umin_(u.z, u.w));
    if (__all((int)(m >= tg))) return;
    if (++it > 4) __builtin_amdgcn_s_sleep(1);
  }
}

// Poll fg1 until >= tg1 while also sampling fg0 >= tg0 in the same pipelined
// round. Returns whether fg0 held on the final iteration (R8-proven skip).
__device__ inline bool waitf4_dual(const unsigned* fg1, unsigned tg1,
                                   const unsigned* fg0, unsigned tg0) {
  const unsigned* p1 = fg1 + (threadIdx.x & 63) * 32;
  const unsigned* p0 = fg0 + (threadIdx.x & 63) * 32;
  unsigned m1, m0v;
  int it = 0;
  for (;;) {
    floatx4 t1, t0;
    asm volatile("global_load_dwordx4 %0, %2, off sc0 sc1\n\t"
                 "global_load_dwordx4 %1, %3, off sc0 sc1\n\t"
                 "s_waitcnt vmcnt(0)"
                 : "=&v"(t1), "=&v"(t0)
                 : "v"(p1), "v"(p0)
                 : "memory");
    uintx4 u1 = __builtin_bit_cast(uintx4, t1);
    uintx4 u0 = __builtin_bit_cast(uintx4, t0);
    m1 = umin_(umin_(u1.x, u1.y), umin_(u1.z, u1.w));
    m0v = umin_(umin_(u0.x, u0.y), umin_(u0.z, u0.w));
    if (__all((int)(m1 >= tg1))) break;
    if (++it > 4) __builtin_amdgcn_s_sleep(1);
  }
  return (bool)__all((int)(m0v >= tg0));
}

__device__ inline floatx4 mfma16(half8 a, half8 b, floatx4 c) {
  return __builtin_amdgcn_mfma_f32_16x16x32_f16(a, b, c, 0, 0, 0);
}

__global__ void init_kernel(const float* __restrict__ x, const float* __restrict__ hc,
                            _Float16* __restrict__ x16, _Float16* __restrict__ h0b,
                            _Float16* __restrict__ h1b, unsigned* __restrict__ flagbase) {
  size_t i = (size_t)blockIdx.x * blockDim.x + threadIdx.x;
  size_t stride = (size_t)gridDim.x * blockDim.x;
  // x -> frag-linear fp16: chunk n = (t*64+row)*32 + cc covers cols 8cc..8cc+7.
  const size_t nch = (size_t)T_STEPS * 64 * 32;
  for (size_t n = i; n < nch; n += stride) {
    size_t tr = n >> 5;          // t*64+row
    int cc = (int)(n & 31);
    int row = (int)(tr & 63);
    size_t t = tr >> 6;
    const float* src = x + (tr * 256 + (size_t)cc * 8);
    floatx4 v0 = *(const floatx4*)src;
    floatx4 v1 = *(const floatx4*)(src + 4);
    half8 h;
    h[0] = (_Float16)v0.x; h[1] = (_Float16)v0.y; h[2] = (_Float16)v0.z; h[3] = (_Float16)v0.w;
    h[4] = (_Float16)v1.x; h[5] = (_Float16)v1.y; h[6] = (_Float16)v1.z; h[7] = (_Float16)v1.w;
    _Float16* dstp = x16 + t * 16384 + (size_t)(row >> 4) * 4096 +
                     (size_t)(cc >> 2) * 512 + (size_t)((row & 15) + 16 * (cc & 3)) * 8;
    *(half8*)dstp = h;
  }
  // h seeds in frag-linear layout (agent-scope stores; consumers use sc1 loads).
  if (i < 8192) {
    int which = (int)(i >> 12);          // 0: h0 seed, 1: h1 seed
    int idx = (int)(i & 4095);           // 64 rows x 64 chunks
    int m = idx >> 6, cc = idx & 63;
    const float* src = hc + (size_t)which * 32768 + (size_t)m * 512 + (size_t)cc * 8;
    union { u64 u[2]; half8 v; } pk;
#pragma unroll
    for (int e = 0; e < 8; ++e) pk.v[e] = (_Float16)src[e];
    _Float16* base = which ? (h1b + 32768) : (h0b + (size_t)(RING - 1) * 32768);
    _Float16* dstp = base + (size_t)(m >> 4) * 8192 + (size_t)(cc >> 2) * 512 +
                     (size_t)((m & 15) + 16 * (cc & 3)) * 8;
    cstore64(dstp, pk.u[0]);
    cstore64(dstp + 4, pk.u[1]);
  }
  if (i < 4096) {  // zero both flag arrays (2 x 8192 B contiguous)
    __hip_atomic_store(flagbase + i, 0u, __ATOMIC_RELAXED, __HIP_MEMORY_SCOPE_AGENT);
  }
}

__global__ __launch_bounds__(256, 1) void lstm_kernel(
    const _Float16* __restrict__ x16, _Float16* __restrict__ h0b, _Float16* __restrict__ h1b,
    unsigned* __restrict__ flags0, unsigned* __restrict__ flags1,
    const float* __restrict__ W_ih0, const float* __restrict__ W_hh0,
    const float* __restrict__ b_ih0, const float* __restrict__ b_hh0,
    const float* __restrict__ W_ih1, const float* __restrict__ W_hh1,
    const float* __restrict__ b_ih1, const float* __restrict__ b_hh1,
    const float* __restrict__ W_out, const float* __restrict__ b_out,
    const float* __restrict__ hc, float* __restrict__ out) {
  __shared__ __align__(16) _Float16 wlds[32 * 1032];

  const int bq = blockIdx.x;
  const bool isL0 = bq < 64;
  const int q = isL0 ? bq : bq - 64;
  const int col0 = q * 8;
  const int Ka = isL0 ? IN_DIM : HID;
  const int K = Ka + HID;
  const int WP = K + 8;
  const int layer = isL0 ? 0 : 1;
  const float* Wa = isL0 ? W_ih0 : W_ih1;
  const float* Wb = isL0 ? W_hh0 : W_hh1;
  const float* bia = isL0 ? b_ih0 : b_ih1;
  const float* bib = isL0 ? b_hh0 : b_hh1;

  for (int idx = threadIdx.x; idx < 32 * K; idx += 256) {
    int r = idx / K;
    int k = idx - r * K;
    int g = r >> 3, j = r & 7;
    int grow = g * HID + col0 + j;  // PyTorch gate order i,f,g,o
    float w = (k < Ka) ? Wa[(size_t)grow * Ka + k] : Wb[(size_t)grow * HID + (k - Ka)];
    wlds[r * WP + k] = (_Float16)w;
  }
  __syncthreads();

  const int lane = threadIdx.x & 63;
  const int wv = threadIdx.x >> 6;   // 0..3
  const int lrow = lane & 15;
  const int kq = (lane >> 4) * 8;
  const _Float16* wrow0 = wlds + lrow * WP;
  const _Float16* wrow1 = wlds + (16 + lrow) * WP;

  // Recurrent-half B fragments in registers/AGPRs (proven R2/R3).
  half8 breg0[16], breg1[16];
#pragma unroll
  for (int c = 0; c < 16; ++c) {
    breg0[c] = *(const half8*)(wrow0 + Ka + c * 32 + kq);
    breg1[c] = *(const half8*)(wrow1 + Ka + c * 32 + kq);
  }

  // Register-gate-phase constants (R8-proven mapping).
  const int bsel = lrow >> 3;
  const int jc = lrow & 7;
  const int rbase = wv * 16 + ((lane >> 4) << 2) + 2 * bsel;
  const int colg = col0 + jc;
  const float bi_ = bia[colg] + bib[colg];
  const float bf_ = bia[HID + colg] + bib[HID + colg];
  const float bg_ = bia[2 * HID + colg] + bib[2 * HID + colg];
  const float bo_ = bia[3 * HID + colg] + bib[3 * HID + colg];
  float cst0 = hc[(size_t)(2 + layer) * 32768 + (size_t)(rbase + 0) * HID + colg];
  float cst1 = hc[(size_t)(2 + layer) * 32768 + (size_t)(rbase + 1) * HID + colg];

  unsigned* myflag = (isL0 ? flags0 : flags1) + q * 32 + wv;

  // Frag-linear per-lane offsets.
  const size_t rd_off = (size_t)wv * 16384 + (size_t)lane * 16;  // bytes
  // Store slot: l = (rbase&15) + 16*(q&3), frag = q>>2, byte-in-chunk = 2*jc.
  const size_t st_off = (size_t)wv * 8192 + (size_t)(q >> 2) * 512 +
                        (size_t)((rbase & 15) + ((q & 3) << 4)) * 8 + jc;  // halfwords

  bool skip0 = false;  // L1: mid-step dual-poll saw flags0 >= t+2 (R8-proven)

  for (int t = 0; t < T_STEPS; ++t) {
    floatx4 acc0 = {0.f, 0.f, 0.f, 0.f};
    floatx4 acc1 = {0.f, 0.f, 0.f, 0.f};
    _Float16* dst;
    half8 f[16];

    if (isL0) {
      // X phase (no cross-block dep): coalesced frag-linear plain loads.
      const _Float16* xw = x16 + (size_t)t * 16384 + (size_t)wv * 4096 + (size_t)lane * 8;
#pragma unroll
      for (int c = 0; c < 8; ++c) {
        half8 a = *(const half8*)(xw + c * 512);
        half8 b0v = *(const half8*)(wrow0 + c * 32 + kq);
        half8 b1v = *(const half8*)(wrow1 + c * 32 + kq);
        acc0 = mfma16(a, b0v, acc0);
        acc1 = mfma16(a, b1v, acc1);
      }
      // Merged wait: wave0 -> peers' h0[t-1]; wave1 -> ring slot free.
      if (threadIdx.x < 64) waitf4(flags0, (unsigned)t);
      else if (threadIdx.x < 128) waitf4(flags1, (t >= RING) ? (unsigned)(t - RING + 1) : 0u);
      __syncthreads();
      asm volatile("" ::: "memory");
      const char* a1p = (const char*)(h0b + (size_t)((t - 1) & (RING - 1)) * 32768) + rd_off;
      ldfrag16(a1p, f);
#pragma unroll
      for (int c = 0; c < 16; ++c) {
        acc0 = mfma16(f[c], breg0[c], acc0);
        acc1 = mfma16(f[c], breg1[c], acc1);
      }
      dst = h0b + (size_t)(t & (RING - 1)) * 32768;
    } else {
      if (threadIdx.x < 64 && !skip0) waitf4(flags0, (unsigned)(t + 1));  // h0[t] ready
      __syncthreads();
      asm volatile("" ::: "memory");
      const char* a0p = (const char*)(h0b + (size_t)(t & (RING - 1)) * 32768) + rd_off;
      ldfrag16(a0p, f);
#pragma unroll
      for (int c = 0; c < 16; ++c) {
        half8 b0v = *(const half8*)(wrow0 + c * 32 + kq);
        half8 b1v = *(const half8*)(wrow1 + c * 32 + kq);
        acc0 = mfma16(f[c], b0v, acc0);
        acc1 = mfma16(f[c], b1v, acc1);
      }
      // flags1 wait AFTER the h0 phase (R4/R8-proven placement); same round
      // samples flags0>=t+2 so next step's top wait is usually skipped.
      if (threadIdx.x < 64)
        skip0 = waitf4_dual(flags1, (unsigned)t, flags0, (unsigned)(t + 2));
      __syncthreads();
      asm volatile("" ::: "memory");
      const char* a1p = (const char*)(h1b + (size_t)((t - 1) & 1) * 32768) + rd_off;
      ldfrag16(a1p, f);
#pragma unroll
      for (int c = 0; c < 16; ++c) {
        acc0 = mfma16(f[c], breg0[c], acc0);
        acc1 = mfma16(f[c], breg1[c], acc1);
      }
      dst = h1b + (size_t)(t & 1) * 32768;
    }

    // ---- register gate phase (R8-proven) ----
    float s00 = __shfl_xor(bsel ? (float)acc0[0] : (float)acc0[2], 8);
    float s01 = __shfl_xor(bsel ? (float)acc0[1] : (float)acc0[3], 8);
    float s10 = __shfl_xor(bsel ? (float)acc1[0] : (float)acc1[2], 8);
    float s11 = __shfl_xor(bsel ? (float)acc1[1] : (float)acc1[3], 8);
    float hv0, hv1;
    {
      float o0 = bsel ? (float)acc0[2] : (float)acc0[0];
      float o1 = bsel ? (float)acc1[2] : (float)acc1[0];
      float gi = bsel ? s00 : o0;
      float gf = bsel ? o0 : s00;
      float gg = bsel ? s10 : o1;
      float go = bsel ? o1 : s10;
      float c = sig_f(gf + bf_) * cst0 + sig_f(gi + bi_) * tanh_f(gg + bg_);
      cst0 = c;
      hv0 = sig_f(go + bo_) * tanh_f(c);
    }
    {
      float o0 = bsel ? (float)acc0[3] : (float)acc0[1];
      float o1 = bsel ? (float)acc1[3] : (float)acc1[1];
      float gi = bsel ? s01 : o0;
      float gf = bsel ? o0 : s01;
      float gg = bsel ? s11 : o1;
      float go = bsel ? o1 : s11;
      float c = sig_f(gf + bf_) * cst1 + sig_f(gi + bi_) * tanh_f(gg + bg_);
      cst1 = c;
      hv1 = sig_f(go + bo_) * tanh_f(c);
    }
    // Pack adjacent columns (lane^1) so even-jc lanes store 4B pairs into the
    // frag-linear slots; row rbase+1 is +8 halfwords (l+1).
    float hx0 = __shfl_xor(hv0, 1);
    float hx1 = __shfl_xor(hv1, 1);
    if ((jc & 1) == 0) {
      _Float16* sb = dst + st_off;
      cstore_pair(sb, hv0, hx0);
      cstore_pair(sb + 8, hv1, hx1);
    }

    // Release: per-wave drain + per-wave sub-flag; no block barrier (each
    // wave's future reads touch only rows it wrote itself) — R8-proven.
    asm volatile("s_waitcnt vmcnt(0)" ::: "memory");
    if ((threadIdx.x & 63) == 0) {
      __hip_atomic_store(myflag, (unsigned)(t + 1), __ATOMIC_RELAXED,
                         __HIP_MEMORY_SCOPE_AGENT);
    }
    asm volatile("" ::: "memory");
  }

  // Final linear on L0 blocks: out[64,256] = h1[511] @ W_out^T + b_out.
  if (isL0) {
    if (threadIdx.x < 64) waitf4(flags1, (unsigned)T_STEPS);
    __syncthreads();
    asm volatile("" ::: "memory");
    const int oc = q * 4 + (threadIdx.x & 3);
    const int m = threadIdx.x >> 2;
    const float* wrow = W_out + (size_t)oc * HID;
    const _Float16* hbase = h1b + 32768;  // h1[511] at parity 1, frag-linear
    float sum = 0.f;
#pragma unroll 4
    for (int hh = 0; hh < 64; ++hh) {  // chunk hh = cols 8hh..8hh+7
      const _Float16* cp = hbase + (size_t)(m >> 4) * 8192 + (size_t)(hh >> 2) * 512 +
                           (size_t)((m & 15) + 16 * (hh & 3)) * 8;
      half8 hvv = cload_h8(cp);
#pragma unroll
      for (int e = 0; e < 8; ++e) sum += (float)hvv[e] * wrow[hh * 8 + e];
    }
    out[m * 256 + oc] = sum + b_out[oc];
  }
}

extern "C" void kernel_launch(void* const* d_in, const int* in_sizes, int n_in,
                              void* d_out, int out_size, void* d_ws, size_t ws_size,
                              hipStream_t stream) {
  const float* x     = (const float*)d_in[0];
  const float* hc    = (const float*)d_in[1];
  const float* W_ih0 = (const float*)d_in[2];
  const float* W_hh0 = (const float*)d_in[3];
  const float* b_ih0 = (const float*)d_in[4];
  const float* b_hh0 = (const float*)d_in[5];
  const float* W_ih1 = (const float*)d_in[6];
  const float* W_hh1 = (const float*)d_in[7];
  const float* b_ih1 = (const float*)d_in[8];
  const float* b_hh1 = (const float*)d_in[9];
  const float* W_out = (const float*)d_in[10];
  const float* b_out = (const float*)d_in[11];
  float* out = (float*)d_out;

  char* ws = (char*)d_ws;
  _Float16* x16 = (_Float16*)ws;                              // 16 MB (frag-linear)
  _Float16* h0b = (_Float16*)(ws + 16777216);                 // 8 x 64 KB ring
  _Float16* h1b = (_Float16*)(ws + 16777216 + 8 * 65536);     // 2 x 64 KB
  unsigned* flags0 = (unsigned*)(ws + 16777216 + 10 * 65536);           // 8 KB
  unsigned* flags1 = (unsigned*)(ws + 16777216 + 10 * 65536 + 8192);    // 8 KB

  init_kernel<<<2048, 256, 0, stream>>>(x, hc, x16, h0b, h1b, flags0);
  lstm_kernel<<<128, 256, 0, stream>>>(x16, h0b, h1b, flags0, flags1,
                                       W_ih0, W_hh0, b_ih0, b_hh0,
                                       W_ih1, W_hh1, b_ih1, b_hh1,
                                       W_out, b_out, hc, out);
}